// Round 13
// baseline (327.844 us; speedup 1.0000x reference)
//
#include <hip/hip_runtime.h>
#include <stdint.h>

typedef unsigned short u16;
typedef __bf16 bf16x8 __attribute__((ext_vector_type(8)));
typedef float f32x4 __attribute__((ext_vector_type(4)));

#define N_NODES 50000
#define N_PAD   50048      // 391 * 128
#define NUM_E   800000
#define FDIM    256
#define NREL    8
#define NBASE   4
#define NKSTEP  20                     // (4 bases + self-loop) * 4 (BK=64)
#define NSEG    N_NODES                // dst-only segments
#define MTILES  196                    // ceil(N_PAD/256)
#define CSRB    49                     // csr_k blocks (49*1024 = 50176 >= NSEG)

// prep kernel block ranges
#define PREP_FEAT_BLOCKS 12512         // N_PAD*64/256
#define PREP_WT_BLOCKS   1280          // 5*65536/256

__device__ __forceinline__ u16 f2bf(float f) {
  uint32_t u = __float_as_uint(f);
  u += 0x7FFFu + ((u >> 16) & 1u);   // RNE
  return (u16)(u >> 16);
}
__device__ __forceinline__ float bf2f(u16 h) {
  return __uint_as_float(((uint32_t)h) << 16);
}

// async global->LDS, 16B per lane; LDS dest = wave-uniform base + lane*16
__device__ __forceinline__ void gload_lds16(const void* g, void* l) {
  __builtin_amdgcn_global_load_lds(
      (__attribute__((address_space(1))) uint32_t*)(void*)(uintptr_t)g,
      (__attribute__((address_space(3))) uint32_t*)(uintptr_t)l,
      16, 0, 0);
}

// ---- fused prep: feat f32->bf16 (zero-pad), Wb transpose ----
// Wb_all[b][o][i] = weight[b][i][o] (b<4);  Wb_all[4][o][i] = loop_w[i][o]
__global__ __launch_bounds__(256) void prep_k(const float* __restrict__ feat,
                                              const float* __restrict__ weight,
                                              const float* __restrict__ loop_w,
                                              u16* __restrict__ fb,
                                              u16* __restrict__ Wb_all) {
  const int b = blockIdx.x;
  const int tid = threadIdx.x;
  if (b < PREP_FEAT_BLOCKS) {
    int idx = b * 256 + tid;                      // one thread = 4 elems
    int row = idx >> 6;
    int q = (idx & 63) * 4;
    float4 v = make_float4(0.f, 0.f, 0.f, 0.f);
    if (row < N_NODES) v = *reinterpret_cast<const float4*>(feat + (size_t)row * FDIM + q);
    ushort4 h;
    h.x = f2bf(v.x); h.y = f2bf(v.y); h.z = f2bf(v.z); h.w = f2bf(v.w);
    *reinterpret_cast<ushort4*>(fb + (size_t)row * FDIM + q) = h;
  } else {
    int idx = (b - PREP_FEAT_BLOCKS) * 256 + tid;
    int r = idx >> 16, rem = idx & 65535;
    int o = rem >> 8, i = rem & 255;
    float s = (r < NBASE) ? weight[(size_t)r * 65536 + i * 256 + o]
                          : loop_w[i * 256 + o];
    Wb_all[idx] = f2bf(s);
  }
}

// ---- single-kernel CSR build: hist + scan + bucket with grid barriers ----
// 49 blocks x 1024 threads (all co-resident on 256 CUs -> spin barriers safe).
// Cross-block data uses agent-scope atomics (per-XCD L2s not coherent).
__global__ __launch_bounds__(1024) void csr_k(const int* __restrict__ src,
                                              const int* __restrict__ dst,
                                              const int* __restrict__ et,
                                              const float* __restrict__ norm,
                                              int* __restrict__ cnt,
                                              int* __restrict__ bar,
                                              int* __restrict__ rowstart,
                                              int* __restrict__ cursor,
                                              int2* __restrict__ ekv,
                                              int* __restrict__ blocksum) {
  __shared__ int wtot[16], woff[16], sboff[64];
  const int tid = threadIdx.x, bid = blockIdx.x;
  const int lane = tid & 63, w = tid >> 6;
  const int gtid = bid * 1024 + tid;
  const int gthreads = CSRB * 1024;

  auto gbar = [&](int target) {
    __threadfence();
    __syncthreads();
    if (tid == 0) {
      atomicAdd(bar, 1);
      while (atomicAdd(bar, 0) < target) __builtin_amdgcn_s_sleep(2);
    }
    __syncthreads();
    __threadfence();
  };

  // phase 0: histogram of dst (grid-stride)
  for (int e = gtid; e < NUM_E; e += gthreads)
    atomicAdd(&cnt[dst[e]], 1);

  gbar(CSRB);

  // phase 1: in-block exclusive scan of this block's 1024 counts
  const int i = gtid;
  const int v = (i < NSEG)
      ? __hip_atomic_load(&cnt[i], __ATOMIC_RELAXED, __HIP_MEMORY_SCOPE_AGENT)
      : 0;
  int inc = v;
#pragma unroll
  for (int off = 1; off < 64; off <<= 1) {
    int t = __shfl_up(inc, off);
    if (lane >= off) inc += t;
  }
  if (lane == 63) wtot[w] = inc;
  __syncthreads();
  if (w == 0) {
    int tv = (lane < 16) ? wtot[lane] : 0;
    int tinc = tv;
#pragma unroll
    for (int off = 1; off < 16; off <<= 1) {
      int t = __shfl_up(tinc, off);
      if (lane >= off) tinc += t;
    }
    if (lane < 16) woff[lane] = tinc - tv;
    if (lane == 15)
      __hip_atomic_store(&blocksum[bid], tinc, __ATOMIC_RELAXED, __HIP_MEMORY_SCOPE_AGENT);
  }
  __syncthreads();
  const int local_ex = inc - v + woff[w];       // in-block exclusive prefix

  gbar(2 * CSRB);

  // phase 2: every block scans the 49 block sums (one wave), adds offset
  if (tid < 64) {
    int bv = (tid < CSRB)
        ? __hip_atomic_load(&blocksum[tid], __ATOMIC_RELAXED, __HIP_MEMORY_SCOPE_AGENT)
        : 0;
    int binc = bv;
#pragma unroll
    for (int off = 1; off < 64; off <<= 1) {
      int t = __shfl_up(binc, off);
      if (tid >= off) binc += t;
    }
    sboff[tid] = binc - bv;
  }
  __syncthreads();
  const int boff = sboff[bid];
  if (i < NSEG) {
    const int rv = local_ex + boff;
    rowstart[i] = rv;                           // consumed by agg_G (next kernel)
    __hip_atomic_store(&cursor[i], rv, __ATOMIC_RELAXED, __HIP_MEMORY_SCOPE_AGENT);
  }
  if (i == NSEG) rowstart[NSEG] = NUM_E;

  gbar(3 * CSRB);

  // phase 3: bucket edges into CSR order (grid-stride)
  for (int e = gtid; e < NUM_E; e += gthreads) {
    const int pos = atomicAdd(&cursor[dst[e]], 1);
    int2 kv;
    kv.x = src[e] * NREL + et[e];
    kv.y = __float_as_int(norm[e]);
    ekv[pos] = kv;                              // consumed next kernel
  }
}

// ---- aggregate into base channels (round-7 proven form; ekv int2 load):
//      G[d][b][:] = sum_{e->d} norm_e * w_comp[et_e][b] * feat[src_e][:]
//      one wave per dst node, 1-ahead prefetch of the gather row ----
__global__ __launch_bounds__(256) void agg_G(const u16* __restrict__ feat_bf,
                                             const int* __restrict__ rowstart,
                                             const int2* __restrict__ ekv,
                                             const float* __restrict__ w_comp,
                                             u16* __restrict__ G) {
  __shared__ float wcs[NREL * NBASE];
  if (threadIdx.x < NREL * NBASE) wcs[threadIdx.x] = w_comp[threadIdx.x];
  __syncthreads();
  const int n = blockIdx.x * 4 + (threadIdx.x >> 6);   // grid exact: n < N_NODES
  const int lane = threadIdx.x & 63;
  const int beg = rowstart[n], end = rowstart[n + 1];

  f32x4 acc[NBASE] = {};
  for (int base = beg; base < end; base += 64) {
    const int m = min(64, end - base);
    int kv = 0; float nv = 0.f;
    if (lane < m) {
      const int2 e = ekv[base + lane];
      kv = e.x; nv = __int_as_float(e.y);
    }
    int key = __shfl(kv, 0);
    float nm = __shfl(nv, 0);
    ushort4 h = *reinterpret_cast<const ushort4*>(
        feat_bf + (size_t)(key >> 3) * FDIM + lane * 4);
    for (int j = 0; j < m; ++j) {
      ushort4 h2; int key2 = 0; float nm2 = 0.f;
      if (j + 1 < m) {
        key2 = __shfl(kv, j + 1);
        nm2 = __shfl(nv, j + 1);
        h2 = *reinterpret_cast<const ushort4*>(
            feat_bf + (size_t)(key2 >> 3) * FDIM + lane * 4);
      }
      const int et = key & 7;
      const float f0 = bf2f(h.x), f1 = bf2f(h.y), f2 = bf2f(h.z), f3 = bf2f(h.w);
#pragma unroll
      for (int bb = 0; bb < NBASE; ++bb) {
        const float c = nm * wcs[et * NBASE + bb];
        acc[bb][0] += f0 * c;
        acc[bb][1] += f1 * c;
        acc[bb][2] += f2 * c;
        acc[bb][3] += f3 * c;
      }
      h = h2; key = key2; nm = nm2;
    }
  }
#pragma unroll
  for (int bb = 0; bb < NBASE; ++bb) {
    ushort4 hh;
    hh.x = f2bf(acc[bb][0]);
    hh.y = f2bf(acc[bb][1]);
    hh.z = f2bf(acc[bb][2]);
    hh.w = f2bf(acc[bb][3]);
    *reinterpret_cast<ushort4*>(G + (size_t)n * (NBASE * FDIM) + bb * FDIM + lane * 4) = hh;
  }
}

// ---- fused GEMM (round-7 proven): out = relu( sum_b G_b@V_b + feat@lw + bias )
//      BM=256, BN=256, BK=64, K=1280 (20 steps), 8 waves (2Mx4N), wave tile 128x64.
//      Double-buffered LDS, stage-early, both-sides XOR swizzle (0 conflicts). ----
__global__ __launch_bounds__(512, 2) void fused_gemm(const u16* __restrict__ G,
                                                     const u16* __restrict__ feat_bf,
                                                     const u16* __restrict__ Wb_all,
                                                     const float* __restrict__ bias,
                                                     float* __restrict__ out) {
  __shared__ __align__(16) u16 As[2][256 * 64];   // 2 x 32 KB
  __shared__ __align__(16) u16 Bs[2][256 * 64];   // 2 x 32 KB
  const int tid = threadIdx.x;
  const int lane = tid & 63;
  const int w = tid >> 6;          // 0..7
  const int wm = w >> 2, wn = w & 3;
  const int mtile = blockIdx.x;

  // per-thread staging constants (source pre-swizzle)
  const int srow = tid >> 3;                      // 0..63: row within 64-row group
  const int scolx = ((tid & 7) << 3) ^ ((srow & 7) << 3);  // swizzled elem col

  f32x4 acc[8][4] = {};

  // stage K-step ks into buffer buf: A 256x64 from G/feat, B 256x64 from Wb_all
  auto stage = [&](int ks, int buf) {
    const int r = ks >> 2, kk4 = ks & 3;
    const int kcol = kk4 * 64 + scolx;
#pragma unroll
    for (int q = 0; q < 4; ++q) {
      const int arow = q * 64 + srow;             // 0..255 within tile
      int gr = mtile * 256 + arow;
      if (gr >= N_PAD) gr = N_PAD - 1;            // clamp (garbage rows discarded)
      const u16* asrc = (r < NBASE)
          ? G + (size_t)gr * 1024 + r * 256 + kcol
          : feat_bf + (size_t)gr * 256 + kcol;
      gload_lds16(asrc, &As[buf][q * 4096 + tid * 8]);
      const u16* bsrc = Wb_all + (size_t)r * 65536 + (size_t)arow * 256 + kcol;
      gload_lds16(bsrc, &Bs[buf][q * 4096 + tid * 8]);
    }
  };

  stage(0, 0);
  __syncthreads();
  for (int t = 0; t < NKSTEP; ++t) {
    const int cur = t & 1;
    if (t + 1 < NKSTEP) stage(t + 1, cur ^ 1);    // flight hidden under compute
#pragma unroll
    for (int kk = 0; kk < 2; ++kk) {
      const int colx = (kk * 32 + ((lane >> 4) << 3)) ^ ((lane & 7) << 3);
      bf16x8 a[8], b[4];
#pragma unroll
      for (int mf = 0; mf < 8; ++mf)
        a[mf] = *reinterpret_cast<const bf16x8*>(
            &As[cur][(wm * 128 + mf * 16 + (lane & 15)) * 64 + colx]);
#pragma unroll
      for (int nf = 0; nf < 4; ++nf)
        b[nf] = *reinterpret_cast<const bf16x8*>(
            &Bs[cur][(wn * 64 + nf * 16 + (lane & 15)) * 64 + colx]);
      __builtin_amdgcn_s_setprio(1);
#pragma unroll
      for (int mf = 0; mf < 8; ++mf)
#pragma unroll
        for (int nf = 0; nf < 4; ++nf)
          acc[mf][nf] = __builtin_amdgcn_mfma_f32_16x16x32_bf16(b[nf], a[mf], acc[mf][nf], 0, 0, 0);
      __builtin_amdgcn_s_setprio(0);
    }
    __syncthreads();                              // drains stage + read-protect
  }

  // epilogue: out = relu(acc + bias); D col(lane&15)=m, o lane-sequential
#pragma unroll
  for (int mf = 0; mf < 8; ++mf) {
    const int m = mtile * 256 + wm * 128 + mf * 16 + (lane & 15);
    if (m >= N_NODES) continue;
#pragma unroll
    for (int nf = 0; nf < 4; ++nf) {
      const int o0 = wn * 64 + nf * 16 + ((lane >> 4) << 2);
      const float4 bv = *reinterpret_cast<const float4*>(bias + o0);
      float4 v;
      v.x = fmaxf(acc[mf][nf][0] + bv.x, 0.f);
      v.y = fmaxf(acc[mf][nf][1] + bv.y, 0.f);
      v.z = fmaxf(acc[mf][nf][2] + bv.z, 0.f);
      v.w = fmaxf(acc[mf][nf][3] + bv.w, 0.f);
      *reinterpret_cast<float4*>(out + (size_t)m * 256 + o0) = v;
    }
  }
}

extern "C" void kernel_launch(void* const* d_in, const int* in_sizes, int n_in,
                              void* d_out, int out_size, void* d_ws, size_t ws_size,
                              hipStream_t stream) {
  (void)in_sizes; (void)n_in; (void)out_size; (void)ws_size;
  const float* feat   = (const float*)d_in[0];
  const float* weight = (const float*)d_in[1];
  const float* w_comp = (const float*)d_in[2];
  const float* loop_w = (const float*)d_in[3];
  const float* h_bias = (const float*)d_in[4];
  const float* norm   = (const float*)d_in[5];
  const int*   src    = (const int*)d_in[6];
  const int*   dst    = (const int*)d_in[7];
  const int*   et     = (const int*)d_in[8];
  float* out = (float*)d_out;

  char* ws = (char*)d_ws;
  u16*   feat_bf  = (u16*)(ws);                      // 25,624,576
  u16*   Wb_all   = (u16*)(ws + 25624576);           //    655,360
  u16*   G        = (u16*)(ws + 26279936);           // 102,498,304 (N_PAD*1024*2)
  int*   counts   = (int*)(ws + 128778240);          //    200,000 (NSEG ints)
  int*   bar      = (int*)(ws + 128978240);          //          4 (+pad to 128978432)
  int*   rowstart = (int*)(ws + 128978432);          //    200,448 (NSEG+1, padded)
  int*   cursor   = (int*)(ws + 129178880);          //    200,192
  int2*  ekv      = (int2*)(ws + 129379072);         //  6,400,000
  int*   blocksum = (int*)(ws + 135779072);          //        256

  // zero counts + barrier counter (one async memset)
  hipMemsetAsync(counts, 0, NSEG * sizeof(int) + 192, stream);

  // prep: feat->bf16, Wb transpose
  prep_k<<<PREP_FEAT_BLOCKS + PREP_WT_BLOCKS, 256, 0, stream>>>(
      feat, weight, loop_w, feat_bf, Wb_all);

  // CSR build (hist + scan + bucket, single kernel, internal grid barriers)
  csr_k<<<CSRB, 1024, 0, stream>>>(src, dst, et, norm, counts, bar,
                                   rowstart, cursor, ekv, blocksum);

  // aggregate into 4 base channels (round-7 proven kernel)
  agg_G<<<N_NODES / 4, 256, 0, stream>>>(feat_bf, rowstart, ekv, w_comp, G);

  // one fused GEMM: K = 4 bases + self-loop; bias + relu fused
  fused_gemm<<<MTILES, 512, 0, stream>>>(G, feat_bf, Wb_all, h_bias, out);
}

// Round 14
// 233.470 us; speedup vs baseline: 1.4042x; 1.4042x over previous
//
#include <hip/hip_runtime.h>
#include <stdint.h>

typedef unsigned short u16;
typedef __bf16 bf16x8 __attribute__((ext_vector_type(8)));
typedef float f32x4 __attribute__((ext_vector_type(4)));

#define N_NODES 50000
#define N_PAD   50048      // 391 * 128
#define NUM_E   800000
#define FDIM    256
#define NREL    8
#define NBASE   4
#define NKSTEP  20                     // (4 bases + self-loop) * 4 (BK=64)
#define NSEG    N_NODES                // dst-only segments
#define NBLK    49                     // ceil(NSEG/1024)
#define MTILES  196                    // ceil(N_PAD/256)

// prep kernel block ranges: feat conv | Wb build | dst histogram
#define PREP_FEAT_BLOCKS 12512         // N_PAD*64/256
#define PREP_WT_BLOCKS   1280          // 5*65536/256
#define PREP_HIST_BLOCKS 3125          // NUM_E/256

__device__ __forceinline__ u16 f2bf(float f) {
  uint32_t u = __float_as_uint(f);
  u += 0x7FFFu + ((u >> 16) & 1u);   // RNE
  return (u16)(u >> 16);
}
__device__ __forceinline__ float bf2f(u16 h) {
  return __uint_as_float(((uint32_t)h) << 16);
}

// async global->LDS, 16B per lane; LDS dest = wave-uniform base + lane*16
__device__ __forceinline__ void gload_lds16(const void* g, void* l) {
  __builtin_amdgcn_global_load_lds(
      (__attribute__((address_space(1))) uint32_t*)(void*)(uintptr_t)g,
      (__attribute__((address_space(3))) uint32_t*)(uintptr_t)l,
      16, 0, 0);
}

// ---- fused prep: feat f32->bf16 (zero-pad), Wb transpose, dst histogram ----
// counts must be pre-zeroed (memset before this kernel).
__global__ __launch_bounds__(256) void prep_k(const float* __restrict__ feat,
                                              const float* __restrict__ weight,
                                              const float* __restrict__ loop_w,
                                              const int* __restrict__ dst,
                                              u16* __restrict__ fb,
                                              u16* __restrict__ Wb_all,
                                              int* __restrict__ cnt) {
  const int b = blockIdx.x;
  const int tid = threadIdx.x;
  if (b < PREP_FEAT_BLOCKS) {
    int idx = b * 256 + tid;                      // one thread = 4 elems
    int row = idx >> 6;
    int q = (idx & 63) * 4;
    float4 v = make_float4(0.f, 0.f, 0.f, 0.f);
    if (row < N_NODES) v = *reinterpret_cast<const float4*>(feat + (size_t)row * FDIM + q);
    ushort4 h;
    h.x = f2bf(v.x); h.y = f2bf(v.y); h.z = f2bf(v.z); h.w = f2bf(v.w);
    *reinterpret_cast<ushort4*>(fb + (size_t)row * FDIM + q) = h;
  } else if (b < PREP_FEAT_BLOCKS + PREP_WT_BLOCKS) {
    int idx = (b - PREP_FEAT_BLOCKS) * 256 + tid;
    int r = idx >> 16, rem = idx & 65535;
    int o = rem >> 8, i = rem & 255;
    float s = (r < NBASE) ? weight[(size_t)r * 65536 + i * 256 + o]
                          : loop_w[i * 256 + o];
    Wb_all[idx] = f2bf(s);
  } else {
    int e = (b - PREP_FEAT_BLOCKS - PREP_WT_BLOCKS) * 256 + tid;
    if (e < NUM_E) atomicAdd(&cnt[dst[e]], 1);
  }
}

// block-level scan (1024/block): rowstart[i] = in-block exclusive prefix
__global__ __launch_bounds__(1024) void scan1(const int* __restrict__ cnt,
                                              int* __restrict__ rowstart,
                                              int* __restrict__ blocksum) {
  __shared__ int wtot[16], woff[16];
  const int tid = threadIdx.x, lane = tid & 63, w = tid >> 6;
  const int i = blockIdx.x * 1024 + tid;
  const int v = (i < NSEG) ? cnt[i] : 0;
  int inc = v;
#pragma unroll
  for (int off = 1; off < 64; off <<= 1) {
    int t = __shfl_up(inc, off);
    if (lane >= off) inc += t;
  }
  if (lane == 63) wtot[w] = inc;
  __syncthreads();
  if (w == 0) {
    int tv = (lane < 16) ? wtot[lane] : 0;
    int tinc = tv;
#pragma unroll
    for (int off = 1; off < 16; off <<= 1) {
      int t = __shfl_up(tinc, off);
      if (lane >= off) tinc += t;
    }
    if (lane < 16) woff[lane] = tinc - tv;
    if (lane == 15) blocksum[blockIdx.x] = tinc;
  }
  __syncthreads();
  if (i < NSEG) rowstart[i] = inc - v + woff[w];
}

// exclusive scan of the block sums (single block)
__global__ __launch_bounds__(512) void scan2(int* __restrict__ blocksum) {
  __shared__ int s[512];
  const int tid = threadIdx.x;
  const int v = (tid < NBLK) ? blocksum[tid] : 0;
  s[tid] = v;
#pragma unroll
  for (int off = 1; off < 512; off <<= 1) {
    __syncthreads();
    int t = (tid >= off) ? s[tid - off] : 0;
    __syncthreads();
    s[tid] += t;
  }
  if (tid < NBLK) blocksum[tid] = s[tid] - v;
}

// add block offsets in place; init cursor; terminator
__global__ __launch_bounds__(1024) void scan3(int* __restrict__ rowstart,
                                              const int* __restrict__ blockoff,
                                              int* __restrict__ cursor) {
  const int i = blockIdx.x * 1024 + threadIdx.x;
  if (i < NSEG) {
    const int v = rowstart[i] + blockoff[i >> 10];
    rowstart[i] = v;
    cursor[i] = v;
  }
  if (i == NSEG) rowstart[NSEG] = NUM_E;
}

// bucket edges into CSR order: one int2 per edge {src*8+etype, norm bits}
__global__ __launch_bounds__(256) void bucket_k(const int* __restrict__ src,
                                                const int* __restrict__ dst,
                                                const int* __restrict__ et,
                                                const float* __restrict__ norm,
                                                int* __restrict__ cursor,
                                                int2* __restrict__ ekv) {
  int e = blockIdx.x * 256 + threadIdx.x;
  if (e >= NUM_E) return;
  const int pos = atomicAdd(&cursor[dst[e]], 1);
  int2 kv;
  kv.x = src[e] * NREL + et[e];
  kv.y = __float_as_int(norm[e]);
  ekv[pos] = kv;
}

// ---- aggregate into base channels (round-7 proven form; int2 descriptor):
//      G[d][b][:] = sum_{e->d} norm_e * w_comp[et_e][b] * feat[src_e][:]
//      one wave per dst node, 1-ahead prefetch of the gather row ----
__global__ __launch_bounds__(256) void agg_G(const u16* __restrict__ feat_bf,
                                             const int* __restrict__ rowstart,
                                             const int2* __restrict__ ekv,
                                             const float* __restrict__ w_comp,
                                             u16* __restrict__ G) {
  __shared__ float wcs[NREL * NBASE];
  if (threadIdx.x < NREL * NBASE) wcs[threadIdx.x] = w_comp[threadIdx.x];
  __syncthreads();
  const int n = blockIdx.x * 4 + (threadIdx.x >> 6);   // grid exact: n < N_NODES
  const int lane = threadIdx.x & 63;
  const int beg = rowstart[n], end = rowstart[n + 1];

  f32x4 acc[NBASE] = {};
  for (int base = beg; base < end; base += 64) {
    const int m = min(64, end - base);
    int kv = 0; float nv = 0.f;
    if (lane < m) {
      const int2 e = ekv[base + lane];
      kv = e.x; nv = __int_as_float(e.y);
    }
    int key = __shfl(kv, 0);
    float nm = __shfl(nv, 0);
    ushort4 h = *reinterpret_cast<const ushort4*>(
        feat_bf + (size_t)(key >> 3) * FDIM + lane * 4);
    for (int j = 0; j < m; ++j) {
      ushort4 h2; int key2 = 0; float nm2 = 0.f;
      if (j + 1 < m) {
        key2 = __shfl(kv, j + 1);
        nm2 = __shfl(nv, j + 1);
        h2 = *reinterpret_cast<const ushort4*>(
            feat_bf + (size_t)(key2 >> 3) * FDIM + lane * 4);
      }
      const int et = key & 7;
      const float f0 = bf2f(h.x), f1 = bf2f(h.y), f2 = bf2f(h.z), f3 = bf2f(h.w);
#pragma unroll
      for (int bb = 0; bb < NBASE; ++bb) {
        const float c = nm * wcs[et * NBASE + bb];
        acc[bb][0] += f0 * c;
        acc[bb][1] += f1 * c;
        acc[bb][2] += f2 * c;
        acc[bb][3] += f3 * c;
      }
      h = h2; key = key2; nm = nm2;
    }
  }
#pragma unroll
  for (int bb = 0; bb < NBASE; ++bb) {
    ushort4 hh;
    hh.x = f2bf(acc[bb][0]);
    hh.y = f2bf(acc[bb][1]);
    hh.z = f2bf(acc[bb][2]);
    hh.w = f2bf(acc[bb][3]);
    *reinterpret_cast<ushort4*>(G + (size_t)n * (NBASE * FDIM) + bb * FDIM + lane * 4) = hh;
  }
}

// ---- fused GEMM (round-7 proven): out = relu( sum_b G_b@V_b + feat@lw + bias )
//      BM=256, BN=256, BK=64, K=1280 (20 steps), 8 waves (2Mx4N), wave tile 128x64.
//      Double-buffered LDS, stage-early, both-sides XOR swizzle (0 conflicts). ----
__global__ __launch_bounds__(512, 2) void fused_gemm(const u16* __restrict__ G,
                                                     const u16* __restrict__ feat_bf,
                                                     const u16* __restrict__ Wb_all,
                                                     const float* __restrict__ bias,
                                                     float* __restrict__ out) {
  __shared__ __align__(16) u16 As[2][256 * 64];   // 2 x 32 KB
  __shared__ __align__(16) u16 Bs[2][256 * 64];   // 2 x 32 KB
  const int tid = threadIdx.x;
  const int lane = tid & 63;
  const int w = tid >> 6;          // 0..7
  const int wm = w >> 2, wn = w & 3;
  const int mtile = blockIdx.x;

  // per-thread staging constants (source pre-swizzle)
  const int srow = tid >> 3;                      // 0..63: row within 64-row group
  const int scolx = ((tid & 7) << 3) ^ ((srow & 7) << 3);  // swizzled elem col

  f32x4 acc[8][4] = {};

  // stage K-step ks into buffer buf: A 256x64 from G/feat, B 256x64 from Wb_all
  auto stage = [&](int ks, int buf) {
    const int r = ks >> 2, kk4 = ks & 3;
    const int kcol = kk4 * 64 + scolx;
#pragma unroll
    for (int q = 0; q < 4; ++q) {
      const int arow = q * 64 + srow;             // 0..255 within tile
      int gr = mtile * 256 + arow;
      if (gr >= N_PAD) gr = N_PAD - 1;            // clamp (garbage rows discarded)
      const u16* asrc = (r < NBASE)
          ? G + (size_t)gr * 1024 + r * 256 + kcol
          : feat_bf + (size_t)gr * 256 + kcol;
      gload_lds16(asrc, &As[buf][q * 4096 + tid * 8]);
      const u16* bsrc = Wb_all + (size_t)r * 65536 + (size_t)arow * 256 + kcol;
      gload_lds16(bsrc, &Bs[buf][q * 4096 + tid * 8]);
    }
  };

  stage(0, 0);
  __syncthreads();
  for (int t = 0; t < NKSTEP; ++t) {
    const int cur = t & 1;
    if (t + 1 < NKSTEP) stage(t + 1, cur ^ 1);    // flight hidden under compute
#pragma unroll
    for (int kk = 0; kk < 2; ++kk) {
      const int colx = (kk * 32 + ((lane >> 4) << 3)) ^ ((lane & 7) << 3);
      bf16x8 a[8], b[4];
#pragma unroll
      for (int mf = 0; mf < 8; ++mf)
        a[mf] = *reinterpret_cast<const bf16x8*>(
            &As[cur][(wm * 128 + mf * 16 + (lane & 15)) * 64 + colx]);
#pragma unroll
      for (int nf = 0; nf < 4; ++nf)
        b[nf] = *reinterpret_cast<const bf16x8*>(
            &Bs[cur][(wn * 64 + nf * 16 + (lane & 15)) * 64 + colx]);
      __builtin_amdgcn_s_setprio(1);
#pragma unroll
      for (int mf = 0; mf < 8; ++mf)
#pragma unroll
        for (int nf = 0; nf < 4; ++nf)
          acc[mf][nf] = __builtin_amdgcn_mfma_f32_16x16x32_bf16(b[nf], a[mf], acc[mf][nf], 0, 0, 0);
      __builtin_amdgcn_s_setprio(0);
    }
    __syncthreads();                              // drains stage + read-protect
  }

  // epilogue: out = relu(acc + bias); D col(lane&15)=m, o lane-sequential
#pragma unroll
  for (int mf = 0; mf < 8; ++mf) {
    const int m = mtile * 256 + wm * 128 + mf * 16 + (lane & 15);
    if (m >= N_NODES) continue;
#pragma unroll
    for (int nf = 0; nf < 4; ++nf) {
      const int o0 = wn * 64 + nf * 16 + ((lane >> 4) << 2);
      const float4 bv = *reinterpret_cast<const float4*>(bias + o0);
      float4 v;
      v.x = fmaxf(acc[mf][nf][0] + bv.x, 0.f);
      v.y = fmaxf(acc[mf][nf][1] + bv.y, 0.f);
      v.z = fmaxf(acc[mf][nf][2] + bv.z, 0.f);
      v.w = fmaxf(acc[mf][nf][3] + bv.w, 0.f);
      *reinterpret_cast<float4*>(out + (size_t)m * 256 + o0) = v;
    }
  }
}

extern "C" void kernel_launch(void* const* d_in, const int* in_sizes, int n_in,
                              void* d_out, int out_size, void* d_ws, size_t ws_size,
                              hipStream_t stream) {
  (void)in_sizes; (void)n_in; (void)out_size; (void)ws_size;
  const float* feat   = (const float*)d_in[0];
  const float* weight = (const float*)d_in[1];
  const float* w_comp = (const float*)d_in[2];
  const float* loop_w = (const float*)d_in[3];
  const float* h_bias = (const float*)d_in[4];
  const float* norm   = (const float*)d_in[5];
  const int*   src    = (const int*)d_in[6];
  const int*   dst    = (const int*)d_in[7];
  const int*   et     = (const int*)d_in[8];
  float* out = (float*)d_out;

  char* ws = (char*)d_ws;
  u16*   feat_bf  = (u16*)(ws);                      // 25,624,576
  u16*   Wb_all   = (u16*)(ws + 25624576);           //    655,360
  u16*   G        = (u16*)(ws + 26279936);           // 102,498,304 (N_PAD*1024*2)
  int*   counts   = (int*)(ws + 128778240);          //    200,192
  int*   rowstart = (int*)(ws + 128978432);          //    200,448 (NSEG+1, padded)
  int*   cursor   = (int*)(ws + 129178880);          //    200,192
  int2*  ekv      = (int2*)(ws + 129379072);         //  6,400,000
  int*   blocksum = (int*)(ws + 135779072);          //        256

  // zero the dst histogram (prep_k's hist range requires it)
  hipMemsetAsync(counts, 0, NSEG * sizeof(int), stream);

  // fused prep: feat->bf16 + Wb transpose + dst histogram (independent ranges)
  prep_k<<<PREP_FEAT_BLOCKS + PREP_WT_BLOCKS + PREP_HIST_BLOCKS, 256, 0, stream>>>(
      feat, weight, loop_w, dst, feat_bf, Wb_all, counts);

  // CSR scan chain + bucket
  scan1<<<NBLK, 1024, 0, stream>>>(counts, rowstart, blocksum);
  scan2<<<1, 512, 0, stream>>>(blocksum);
  scan3<<<NBLK + 1, 1024, 0, stream>>>(rowstart, blocksum, cursor);
  bucket_k<<<(NUM_E + 255) / 256, 256, 0, stream>>>(src, dst, et, norm, cursor, ekv);

  // aggregate into 4 base channels (round-7 proven kernel)
  agg_G<<<N_NODES / 4, 256, 0, stream>>>(feat_bf, rowstart, ekv, w_comp, G);

  // one fused GEMM: K = 4 bases + self-loop; bias + relu fused
  fused_gemm<<<MTILES, 512, 0, stream>>>(G, feat_bf, Wb_all, h_bias, out);
}

// Round 15
// 229.499 us; speedup vs baseline: 1.4285x; 1.0173x over previous
//
#include <hip/hip_runtime.h>
#include <stdint.h>

typedef unsigned short u16;
typedef __bf16 bf16x8 __attribute__((ext_vector_type(8)));
typedef float f32x4 __attribute__((ext_vector_type(4)));

#define N_NODES 50000
#define N_PAD   50048      // 391 * 128 (allocation row count for feat_bf / G)
#define NUM_E   800000
#define FDIM    256
#define NREL    8
#define NBASE   4
#define NKSTEP  20                     // (4 bases + self-loop) * 4 (BK=64)
#define NSEG    N_NODES                // dst-only segments
#define NBLK    49                     // ceil(NSEG/1024)
#define BM      224                    // GEMM M-tile (224 blocks -> all-resident)
#define MTILES  224                    // ceil(50000/224) = 224; 224*224 = 50176

// prep kernel block ranges: feat conv | Wb build | dst histogram
#define PREP_FEAT_BLOCKS 12512         // N_PAD*64/256
#define PREP_WT_BLOCKS   1280          // 5*65536/256
#define PREP_HIST_BLOCKS 3125          // NUM_E/256

__device__ __forceinline__ u16 f2bf(float f) {
  uint32_t u = __float_as_uint(f);
  u += 0x7FFFu + ((u >> 16) & 1u);   // RNE
  return (u16)(u >> 16);
}
__device__ __forceinline__ float bf2f(u16 h) {
  return __uint_as_float(((uint32_t)h) << 16);
}

// async global->LDS, 16B per lane; LDS dest = wave-uniform base + lane*16
__device__ __forceinline__ void gload_lds16(const void* g, void* l) {
  __builtin_amdgcn_global_load_lds(
      (__attribute__((address_space(1))) uint32_t*)(void*)(uintptr_t)g,
      (__attribute__((address_space(3))) uint32_t*)(uintptr_t)l,
      16, 0, 0);
}

// ---- fused prep: feat f32->bf16 (zero-pad), Wb transpose, dst histogram ----
// counts must be pre-zeroed (memset before this kernel).
__global__ __launch_bounds__(256) void prep_k(const float* __restrict__ feat,
                                              const float* __restrict__ weight,
                                              const float* __restrict__ loop_w,
                                              const int* __restrict__ dst,
                                              u16* __restrict__ fb,
                                              u16* __restrict__ Wb_all,
                                              int* __restrict__ cnt) {
  const int b = blockIdx.x;
  const int tid = threadIdx.x;
  if (b < PREP_FEAT_BLOCKS) {
    int idx = b * 256 + tid;                      // one thread = 4 elems
    int row = idx >> 6;
    int q = (idx & 63) * 4;
    float4 v = make_float4(0.f, 0.f, 0.f, 0.f);
    if (row < N_NODES) v = *reinterpret_cast<const float4*>(feat + (size_t)row * FDIM + q);
    ushort4 h;
    h.x = f2bf(v.x); h.y = f2bf(v.y); h.z = f2bf(v.z); h.w = f2bf(v.w);
    *reinterpret_cast<ushort4*>(fb + (size_t)row * FDIM + q) = h;
  } else if (b < PREP_FEAT_BLOCKS + PREP_WT_BLOCKS) {
    int idx = (b - PREP_FEAT_BLOCKS) * 256 + tid;
    int r = idx >> 16, rem = idx & 65535;
    int o = rem >> 8, i = rem & 255;
    float s = (r < NBASE) ? weight[(size_t)r * 65536 + i * 256 + o]
                          : loop_w[i * 256 + o];
    Wb_all[idx] = f2bf(s);
  } else {
    int e = (b - PREP_FEAT_BLOCKS - PREP_WT_BLOCKS) * 256 + tid;
    if (e < NUM_E) atomicAdd(&cnt[dst[e]], 1);
  }
}

// block-level scan (1024/block): rowstart[i] = in-block exclusive prefix
__global__ __launch_bounds__(1024) void scan1(const int* __restrict__ cnt,
                                              int* __restrict__ rowstart,
                                              int* __restrict__ blocksum) {
  __shared__ int wtot[16], woff[16];
  const int tid = threadIdx.x, lane = tid & 63, w = tid >> 6;
  const int i = blockIdx.x * 1024 + tid;
  const int v = (i < NSEG) ? cnt[i] : 0;
  int inc = v;
#pragma unroll
  for (int off = 1; off < 64; off <<= 1) {
    int t = __shfl_up(inc, off);
    if (lane >= off) inc += t;
  }
  if (lane == 63) wtot[w] = inc;
  __syncthreads();
  if (w == 0) {
    int tv = (lane < 16) ? wtot[lane] : 0;
    int tinc = tv;
#pragma unroll
    for (int off = 1; off < 16; off <<= 1) {
      int t = __shfl_up(tinc, off);
      if (lane >= off) tinc += t;
    }
    if (lane < 16) woff[lane] = tinc - tv;
    if (lane == 15) blocksum[blockIdx.x] = tinc;
  }
  __syncthreads();
  if (i < NSEG) rowstart[i] = inc - v + woff[w];
}

// exclusive scan of the block sums (single block)
__global__ __launch_bounds__(512) void scan2(int* __restrict__ blocksum) {
  __shared__ int s[512];
  const int tid = threadIdx.x;
  const int v = (tid < NBLK) ? blocksum[tid] : 0;
  s[tid] = v;
#pragma unroll
  for (int off = 1; off < 512; off <<= 1) {
    __syncthreads();
    int t = (tid >= off) ? s[tid - off] : 0;
    __syncthreads();
    s[tid] += t;
  }
  if (tid < NBLK) blocksum[tid] = s[tid] - v;
}

// add block offsets in place; init cursor; terminator
__global__ __launch_bounds__(1024) void scan3(int* __restrict__ rowstart,
                                              const int* __restrict__ blockoff,
                                              int* __restrict__ cursor) {
  const int i = blockIdx.x * 1024 + threadIdx.x;
  if (i < NSEG) {
    const int v = rowstart[i] + blockoff[i >> 10];
    rowstart[i] = v;
    cursor[i] = v;
  }
  if (i == NSEG) rowstart[NSEG] = NUM_E;
}

// bucket edges into CSR order: one int2 per edge {src*8+etype, norm bits}
__global__ __launch_bounds__(256) void bucket_k(const int* __restrict__ src,
                                                const int* __restrict__ dst,
                                                const int* __restrict__ et,
                                                const float* __restrict__ norm,
                                                int* __restrict__ cursor,
                                                int2* __restrict__ ekv) {
  int e = blockIdx.x * 256 + threadIdx.x;
  if (e >= NUM_E) return;
  const int pos = atomicAdd(&cursor[dst[e]], 1);
  int2 kv;
  kv.x = src[e] * NREL + et[e];
  kv.y = __float_as_int(norm[e]);
  ekv[pos] = kv;
}

// ---- aggregate into base channels (round-7 proven form; int2 descriptor):
//      G[d][b][:] = sum_{e->d} norm_e * w_comp[et_e][b] * feat[src_e][:]
//      one wave per dst node, 1-ahead prefetch of the gather row ----
__global__ __launch_bounds__(256) void agg_G(const u16* __restrict__ feat_bf,
                                             const int* __restrict__ rowstart,
                                             const int2* __restrict__ ekv,
                                             const float* __restrict__ w_comp,
                                             u16* __restrict__ G) {
  __shared__ float wcs[NREL * NBASE];
  if (threadIdx.x < NREL * NBASE) wcs[threadIdx.x] = w_comp[threadIdx.x];
  __syncthreads();
  const int n = blockIdx.x * 4 + (threadIdx.x >> 6);   // grid exact: n < N_NODES
  const int lane = threadIdx.x & 63;
  const int beg = rowstart[n], end = rowstart[n + 1];

  f32x4 acc[NBASE] = {};
  for (int base = beg; base < end; base += 64) {
    const int m = min(64, end - base);
    int kv = 0; float nv = 0.f;
    if (lane < m) {
      const int2 e = ekv[base + lane];
      kv = e.x; nv = __int_as_float(e.y);
    }
    int key = __shfl(kv, 0);
    float nm = __shfl(nv, 0);
    ushort4 h = *reinterpret_cast<const ushort4*>(
        feat_bf + (size_t)(key >> 3) * FDIM + lane * 4);
    for (int j = 0; j < m; ++j) {
      ushort4 h2; int key2 = 0; float nm2 = 0.f;
      if (j + 1 < m) {
        key2 = __shfl(kv, j + 1);
        nm2 = __shfl(nv, j + 1);
        h2 = *reinterpret_cast<const ushort4*>(
            feat_bf + (size_t)(key2 >> 3) * FDIM + lane * 4);
      }
      const int et = key & 7;
      const float f0 = bf2f(h.x), f1 = bf2f(h.y), f2 = bf2f(h.z), f3 = bf2f(h.w);
#pragma unroll
      for (int bb = 0; bb < NBASE; ++bb) {
        const float c = nm * wcs[et * NBASE + bb];
        acc[bb][0] += f0 * c;
        acc[bb][1] += f1 * c;
        acc[bb][2] += f2 * c;
        acc[bb][3] += f3 * c;
      }
      h = h2; key = key2; nm = nm2;
    }
  }
#pragma unroll
  for (int bb = 0; bb < NBASE; ++bb) {
    ushort4 hh;
    hh.x = f2bf(acc[bb][0]);
    hh.y = f2bf(acc[bb][1]);
    hh.z = f2bf(acc[bb][2]);
    hh.w = f2bf(acc[bb][3]);
    *reinterpret_cast<ushort4*>(G + (size_t)n * (NBASE * FDIM) + bb * FDIM + lane * 4) = hh;
  }
}

// ---- fused GEMM: out = relu( sum_b G_b@V_b + feat@lw + bias )
//      BM=224, BN=256, BK=64, K=1280 (20 steps), 8 waves (2Mx4N), wave tile 112x64.
//      224 blocks -> ALL co-resident on 256 CUs (no quantization tail; was 196
//      blocks = 60 idle CUs). Double-buffered LDS (120KB), stage-early,
//      both-sides XOR swizzle (r6-verified: 0 bank conflicts), setprio. ----
__global__ __launch_bounds__(512, 2) void fused_gemm(const u16* __restrict__ G,
                                                     const u16* __restrict__ feat_bf,
                                                     const u16* __restrict__ Wb_all,
                                                     const float* __restrict__ bias,
                                                     float* __restrict__ out) {
  __shared__ __align__(16) u16 As[2][BM * 64];    // 2 x 28 KB
  __shared__ __align__(16) u16 Bs[2][256 * 64];   // 2 x 32 KB
  const int tid = threadIdx.x;
  const int lane = tid & 63;
  const int w = tid >> 6;          // 0..7
  const int wm = w >> 2, wn = w & 3;
  const int mtile = blockIdx.x;

  // per-thread staging constants (source pre-swizzle)
  const int srow = tid >> 3;                      // 0..63: row within 64-row group
  const int scolx = ((tid & 7) << 3) ^ ((srow & 7) << 3);  // swizzled elem col

  f32x4 acc[7][4] = {};

  // stage K-step ks into buffer buf: A 224x64 from G/feat, B 256x64 from Wb_all
  auto stage = [&](int ks, int buf) {
    const int r = ks >> 2, kk4 = ks & 3;
    const int kcol = kk4 * 64 + scolx;
    // A: 3 full 64-row groups + one 32-row group (waves 0-3 only; wave-uniform)
#pragma unroll
    for (int q = 0; q < 4; ++q) {
      if (q == 3 && tid >= 256) break;
      const int arow = q * 64 + srow;             // 0..223 within tile
      int gr = mtile * BM + arow;
      if (gr >= N_PAD) gr = N_PAD - 1;            // clamp (garbage rows discarded)
      const u16* asrc = (r < NBASE)
          ? G + (size_t)gr * 1024 + r * 256 + kcol
          : feat_bf + (size_t)gr * 256 + kcol;
      gload_lds16(asrc, &As[buf][q * 4096 + tid * 8]);
    }
#pragma unroll
    for (int q = 0; q < 4; ++q) {
      const int brow = q * 64 + srow;             // 0..255
      const u16* bsrc = Wb_all + (size_t)r * 65536 + (size_t)brow * 256 + kcol;
      gload_lds16(bsrc, &Bs[buf][q * 4096 + tid * 8]);
    }
  };

  stage(0, 0);
  __syncthreads();
  for (int t = 0; t < NKSTEP; ++t) {
    const int cur = t & 1;
    if (t + 1 < NKSTEP) stage(t + 1, cur ^ 1);    // flight hidden under compute
#pragma unroll
    for (int kk = 0; kk < 2; ++kk) {
      const int colx = (kk * 32 + ((lane >> 4) << 3)) ^ ((lane & 7) << 3);
      bf16x8 a[7], b[4];
#pragma unroll
      for (int mf = 0; mf < 7; ++mf)
        a[mf] = *reinterpret_cast<const bf16x8*>(
            &As[cur][(wm * 112 + mf * 16 + (lane & 15)) * 64 + colx]);
#pragma unroll
      for (int nf = 0; nf < 4; ++nf)
        b[nf] = *reinterpret_cast<const bf16x8*>(
            &Bs[cur][(wn * 64 + nf * 16 + (lane & 15)) * 64 + colx]);
      __builtin_amdgcn_s_setprio(1);
#pragma unroll
      for (int mf = 0; mf < 7; ++mf)
#pragma unroll
        for (int nf = 0; nf < 4; ++nf)
          acc[mf][nf] = __builtin_amdgcn_mfma_f32_16x16x32_bf16(b[nf], a[mf], acc[mf][nf], 0, 0, 0);
      __builtin_amdgcn_s_setprio(0);
    }
    __syncthreads();                              // drains stage + read-protect
  }

  // epilogue: out = relu(acc + bias); D col(lane&15)=m, o lane-sequential
#pragma unroll
  for (int mf = 0; mf < 7; ++mf) {
    const int m = mtile * BM + wm * 112 + mf * 16 + (lane & 15);
    if (m >= N_NODES) continue;
#pragma unroll
    for (int nf = 0; nf < 4; ++nf) {
      const int o0 = wn * 64 + nf * 16 + ((lane >> 4) << 2);
      const float4 bv = *reinterpret_cast<const float4*>(bias + o0);
      float4 v;
      v.x = fmaxf(acc[mf][nf][0] + bv.x, 0.f);
      v.y = fmaxf(acc[mf][nf][1] + bv.y, 0.f);
      v.z = fmaxf(acc[mf][nf][2] + bv.z, 0.f);
      v.w = fmaxf(acc[mf][nf][3] + bv.w, 0.f);
      *reinterpret_cast<float4*>(out + (size_t)m * 256 + o0) = v;
    }
  }
}

extern "C" void kernel_launch(void* const* d_in, const int* in_sizes, int n_in,
                              void* d_out, int out_size, void* d_ws, size_t ws_size,
                              hipStream_t stream) {
  (void)in_sizes; (void)n_in; (void)out_size; (void)ws_size;
  const float* feat   = (const float*)d_in[0];
  const float* weight = (const float*)d_in[1];
  const float* w_comp = (const float*)d_in[2];
  const float* loop_w = (const float*)d_in[3];
  const float* h_bias = (const float*)d_in[4];
  const float* norm   = (const float*)d_in[5];
  const int*   src    = (const int*)d_in[6];
  const int*   dst    = (const int*)d_in[7];
  const int*   et     = (const int*)d_in[8];
  float* out = (float*)d_out;

  char* ws = (char*)d_ws;
  u16*   feat_bf  = (u16*)(ws);                      // 25,624,576
  u16*   Wb_all   = (u16*)(ws + 25624576);           //    655,360
  u16*   G        = (u16*)(ws + 26279936);           // 102,498,304 (N_PAD*1024*2)
  int*   counts   = (int*)(ws + 128778240);          //    200,192
  int*   rowstart = (int*)(ws + 128978432);          //    200,448 (NSEG+1, padded)
  int*   cursor   = (int*)(ws + 129178880);          //    200,192
  int2*  ekv      = (int2*)(ws + 129379072);         //  6,400,000
  int*   blocksum = (int*)(ws + 135779072);          //        256

  // zero the dst histogram (prep_k's hist range requires it)
  hipMemsetAsync(counts, 0, NSEG * sizeof(int), stream);

  // fused prep: feat->bf16 + Wb transpose + dst histogram (independent ranges)
  prep_k<<<PREP_FEAT_BLOCKS + PREP_WT_BLOCKS + PREP_HIST_BLOCKS, 256, 0, stream>>>(
      feat, weight, loop_w, dst, feat_bf, Wb_all, counts);

  // CSR scan chain + bucket
  scan1<<<NBLK, 1024, 0, stream>>>(counts, rowstart, blocksum);
  scan2<<<1, 512, 0, stream>>>(blocksum);
  scan3<<<NBLK + 1, 1024, 0, stream>>>(rowstart, blocksum, cursor);
  bucket_k<<<(NUM_E + 255) / 256, 256, 0, stream>>>(src, dst, et, norm, cursor, ekv);

  // aggregate into 4 base channels (round-7 proven kernel)
  agg_G<<<N_NODES / 4, 256, 0, stream>>>(feat_bf, rowstart, ekv, w_comp, G);

  // one fused GEMM: K = 4 bases + self-loop; bias + relu fused; 224 blocks
  fused_gemm<<<MTILES, 512, 0, stream>>>(G, feat_bf, Wb_all, h_bias, out);
}